// Round 3
// baseline (1862.729 us; speedup 1.0000x reference)
//
#include <hip/hip_runtime.h>
#include <hip/hip_bf16.h>

#define L 512
#define H 128
#define E 256
#define NN 50000
#define NE 600000

// ---------------- static device scratch (graph-capture safe, no ws dependency) ----
__device__ float g_xg[4][L*512];     // [l0f,l0b,l1f,l1b] : xg incl. bih+bhh
__device__ float g_hs[4][L*H];       // hidden outputs per dir-layer
__device__ float g_proj[L*E];
__device__ float g_qkv[L*3*E];
__device__ float g_kmat[E*L];        // kmat[h*64+d][u]
__device__ float g_a511[4*L];        // attn row 511 per head
__device__ float g_molemb[E];
__device__ float g_ssum[H];
__device__ float g_hg[E];
__device__ float g_agg[NN*H];        // agg1, overwritten in-place by relu(agg@W1+b1)
__device__ int   g_cnt_dst[NN];
__device__ int   g_cnt_src[NN];
__device__ int   g_offs[NN+1];
__device__ int   g_cursor[NN];
__device__ int   g_eidx[NE];

__device__ __forceinline__ float sigm(float x){ return 1.f/(1.f+__expf(-x)); }
__device__ __forceinline__ float tanh_f(float x){ float e=__expf(2.f*x); return 1.f - 2.f/(e+1.f); }

// ---------------- GCN ----------------
__global__ void zero_kernel(){
  int i = blockIdx.x*blockDim.x + threadIdx.x;
  if (i < NN){ g_cnt_dst[i]=0; g_cnt_src[i]=0; }
  if (i < H) g_ssum[i]=0.f;
}

__global__ void hist_kernel(const int* __restrict__ src, const int* __restrict__ dst){
  int i = blockIdx.x*blockDim.x + threadIdx.x;
  if (i < NE){
    atomicAdd(&g_cnt_dst[dst[i]], 1);
    atomicAdd(&g_cnt_src[src[i]], 1);
  }
}

__global__ __launch_bounds__(1024) void scan_kernel(){
  __shared__ int part[1024];
  const int t = threadIdx.x;
  const int CH = 49;                       // 1024*49 = 50176 >= 50000
  const int base = t*CH;
  int s = 0;
  for (int i=0;i<CH;i++){ int v=base+i; if (v<NN) s += g_cnt_dst[v]; }
  part[t] = s;
  __syncthreads();
  for (int off=1; off<1024; off<<=1){
    int v = part[t];
    if (t >= off) v += part[t-off];
    __syncthreads();
    part[t] = v;
    __syncthreads();
  }
  int run = part[t] - s;                   // exclusive prefix for this chunk
  for (int i=0;i<CH;i++){
    int v = base+i;
    if (v < NN){ g_offs[v]=run; g_cursor[v]=run; run += g_cnt_dst[v]; }
  }
  if (t == 1023) g_offs[NN] = part[1023];
}

__global__ void fill_kernel(const int* __restrict__ src, const int* __restrict__ dst){
  int i = blockIdx.x*blockDim.x + threadIdx.x;
  if (i < NE){
    int p = atomicAdd(&g_cursor[dst[i]], 1);
    g_eidx[p] = src[i];
  }
}

// one wave per node: coalesced 512B row gathers, no float atomics
__global__ __launch_bounds__(64) void agg_kernel(const float* __restrict__ feat){
  const int v = blockIdx.x;
  const int t = threadIdx.x;              // 64 threads, 2 channels each
  const int s = g_offs[v], e = g_offs[v+1];
  float2 acc = make_float2(0.f, 0.f);
  for (int j=s; j<e; ++j){
    const int sv = g_eidx[j];             // uniform across wave -> broadcast
    float2 x = ((const float2*)(feat + sv*H))[t];
    acc.x += x.x; acc.y += x.y;
  }
  ((float2*)(g_agg + v*H))[t] = acc;
}

// in-place h = relu(agg @ W1 + b1); 8 rows per 256-thread block
__global__ __launch_bounds__(256) void gemm1_kernel(const float* __restrict__ W, const float* __restrict__ b){
  __shared__ __align__(16) float ash[8*H];
  const int tid = threadIdx.x;
  const int base = blockIdx.x * 8;
  for (int i=tid; i<8*H; i+=256) ash[i] = g_agg[base*H + i];
  __syncthreads();
  const int r  = tid >> 5;                // 0..7 local row
  const int j4 = tid & 31;                // output col group (4 cols)
  float4 acc = ((const float4*)b)[j4];
  const float* arow = ash + r*H;
  const float4* W4 = (const float4*)W;
  #pragma unroll 8
  for (int k=0;k<H;++k){
    float4 wv = W4[k*32 + j4];            // coalesced, L1-resident (64KB)
    float av = arow[k];
    acc.x += av*wv.x; acc.y += av*wv.y; acc.z += av*wv.z; acc.w += av*wv.w;
  }
  float4 o = make_float4(fmaxf(acc.x,0.f), fmaxf(acc.y,0.f), fmaxf(acc.z,0.f), fmaxf(acc.w,0.f));
  ((float4*)(g_agg + (base + r)*H))[j4] = o;   // safe: rows staged to LDS first
}

// s[c] = sum_v cnt_src[v]*h[v][c]
__global__ __launch_bounds__(128) void wsum_kernel(){
  const int c = threadIdx.x;
  const int v0 = blockIdx.x * 98;
  const int v1 = (v0+98 < NN) ? v0+98 : NN;
  float acc = 0.f;
  for (int v=v0; v<v1; ++v)
    acc += (float)g_cnt_src[v] * g_agg[v*H + c];
  atomicAdd(&g_ssum[c], acc);
}

// hg = (s/N) @ W2 + b2
__global__ __launch_bounds__(256) void hg_kernel(const float* __restrict__ W2, const float* __restrict__ b2){
  __shared__ float ssh[H];
  const int j = threadIdx.x;
  if (j < H) ssh[j] = g_ssum[j] * (1.f/(float)NN);
  __syncthreads();
  float acc = b2[j];
  #pragma unroll 8
  for (int k=0;k<H;++k) acc += ssh[k]*W2[k*E + j];
  g_hg[j] = acc;
}

// ---------------- BiLSTM ----------------
// layer0 xg: x(512x14) @ Wih.T + bih + bhh
__global__ __launch_bounds__(512) void xg0_kernel(const float* __restrict__ x,
    const float* __restrict__ Wf, const float* __restrict__ bif, const float* __restrict__ bhf,
    const float* __restrict__ Wb, const float* __restrict__ bib, const float* __restrict__ bhb){
  const int t = blockIdx.x, dir = blockIdx.y, j = threadIdx.x;
  __shared__ float xr[14];
  if (j < 14) xr[j] = x[t*14 + j];
  __syncthreads();
  const float* W = dir ? Wb : Wf;
  float acc = dir ? (bib[j]+bhb[j]) : (bif[j]+bhf[j]);
  #pragma unroll
  for (int k=0;k<14;++k) acc += xr[k]*W[j*14 + k];
  g_xg[dir][t*512 + j] = acc;
}

// layer1 xg: concat(hf0,hb0)(512x256) @ Wih1.T + biases
__global__ __launch_bounds__(512) void xg1_kernel(
    const float* __restrict__ Wf, const float* __restrict__ bif, const float* __restrict__ bhf,
    const float* __restrict__ Wb, const float* __restrict__ bib, const float* __restrict__ bhb){
  const int t = blockIdx.x, dir = blockIdx.y, j = threadIdx.x;
  __shared__ __align__(16) float y[E];
  if (j < H) y[j] = g_hs[0][t*H + j];
  else if (j < E) y[j] = g_hs[1][t*H + (j-H)];
  __syncthreads();
  const float* W = dir ? Wb : Wf;
  float acc = dir ? (bib[j]+bhb[j]) : (bif[j]+bhf[j]);
  const float4* w4 = (const float4*)(W + j*E);
  const float4* y4 = (const float4*)y;
  #pragma unroll 8
  for (int k4=0;k4<64;++k4){
    float4 w = w4[k4], p = y4[k4];
    acc += w.x*p.x + w.y*p.y + w.z*p.z + w.w*p.w;
  }
  g_xg[2+dir][t*512 + j] = acc;
}

// sequential LSTM: 1 block per direction, Whh row in VGPRs, h broadcast via LDS
__global__ __launch_bounds__(512) void lstm_kernel(const float* __restrict__ WhhF,
                                                   const float* __restrict__ WhhB, int layer){
  const int dir = blockIdx.x;
  const float* __restrict__ Whh = dir ? WhhB : WhhF;
  const float* __restrict__ xg  = g_xg[layer*2 + dir];
  float* __restrict__ hs        = g_hs[layer*2 + dir];
  const int j = threadIdx.x;
  float w[H];
  {
    const float4* W4 = (const float4*)(Whh + j*H);
    #pragma unroll
    for (int k4=0;k4<32;++k4){
      float4 v = W4[k4];
      w[4*k4]=v.x; w[4*k4+1]=v.y; w[4*k4+2]=v.z; w[4*k4+3]=v.w;
    }
  }
  __shared__ __align__(16) float hsm[H];
  __shared__ float gates[512];
  if (j < H) hsm[j] = 0.f;
  float c = 0.f;
  __syncthreads();
  const int gate = j >> 7;                 // 0:i 1:f 2:g 3:o (wave-uniform)
  int tt0 = dir ? (L-1) : 0;
  float xg_cur = xg[tt0*512 + j];
  for (int t=0; t<L; ++t){
    const int tt = dir ? (L-1-t) : t;
    int ttn = dir ? (L-2-t) : (t+1);
    ttn = ttn < 0 ? 0 : (ttn > L-1 ? L-1 : ttn);
    const float xg_next = xg[ttn*512 + j]; // prefetch, hidden under the dot
    float acc = xg_cur;
    const float4* h4 = (const float4*)hsm;
    #pragma unroll
    for (int k4=0;k4<32;++k4){
      float4 hv = h4[k4];                  // broadcast ds_read_b128
      acc += w[4*k4]*hv.x + w[4*k4+1]*hv.y + w[4*k4+2]*hv.z + w[4*k4+3]*hv.w;
    }
    float a = (gate == 2) ? tanh_f(acc) : sigm(acc);
    gates[j] = a;
    __syncthreads();
    if (j < H){
      c = gates[H+j]*c + gates[j]*gates[2*H+j];
      float hn = gates[3*H+j]*tanh_f(c);
      hsm[j] = hn;
      hs[tt*H + j] = hn;
    }
    __syncthreads();
    xg_cur = xg_next;
  }
}

// ---------------- attention path ----------------
__global__ __launch_bounds__(256) void proj_kernel(const float* __restrict__ fcw, const float* __restrict__ fcb){
  const int t = blockIdx.x, j = threadIdx.x;
  __shared__ __align__(16) float y[E];
  y[j] = (j < H) ? g_hs[2][t*H + j] : g_hs[3][t*H + (j-H)];
  __syncthreads();
  float acc = fcb[j];
  const float4* w4 = (const float4*)(fcw + j*E);
  const float4* y4 = (const float4*)y;
  #pragma unroll 8
  for (int k4=0;k4<64;++k4){
    float4 w = w4[k4], p = y4[k4];
    acc += w.x*p.x + w.y*p.y + w.z*p.z + w.w*p.w;
  }
  g_proj[t*E + j] = acc;
}

__global__ __launch_bounds__(256) void qkv_kernel(const float* __restrict__ inw, const float* __restrict__ inb){
  const int t = blockIdx.x, tid = threadIdx.x;
  __shared__ __align__(16) float pr[E];
  pr[tid] = g_proj[t*E + tid];
  __syncthreads();
  const float4* p4 = (const float4*)pr;
  for (int r=0;r<3;++r){
    const int j = r*E + tid;
    float acc = inb[j];
    const float4* w4 = (const float4*)(inw + j*E);
    #pragma unroll 8
    for (int k4=0;k4<64;++k4){
      float4 w = w4[k4], p = p4[k4];
      acc += w.x*p.x + w.y*p.y + w.z*p.z + w.w*p.w;
    }
    g_qkv[t*3*E + j] = acc;
  }
}

__global__ __launch_bounds__(256) void ktrans_kernel(){
  const int u = blockIdx.x, i = threadIdx.x;
  g_kmat[i*L + u] = g_qkv[u*3*E + E + i];
}

// scores+softmax per row, fused; attn mean over heads -> d_out; row 511 saved
__global__ __launch_bounds__(512) void attn_kernel(float* __restrict__ out){
  const int t = blockIdx.x, u = threadIdx.x;
  const int lane = u & 63, wid = u >> 6;
  __shared__ float qsh[64];
  __shared__ float redm[8], reds[8];
  float accm = 0.f;
  for (int h=0; h<4; ++h){
    __syncthreads();
    if (u < 64) qsh[u] = g_qkv[t*3*E + h*64 + u];
    __syncthreads();
    const float* km = g_kmat + h*64*L + u;
    float s = 0.f;
    #pragma unroll 8
    for (int d=0; d<64; ++d) s += qsh[d]*km[d*L];
    s *= 0.125f;
    float m = s;
    for (int o=32;o;o>>=1) m = fmaxf(m, __shfl_xor(m, o, 64));
    if (lane == 0) redm[wid] = m;
    __syncthreads();
    m = redm[0];
    #pragma unroll
    for (int w2=1;w2<8;++w2) m = fmaxf(m, redm[w2]);
    float e = __expf(s - m);
    float sum = e;
    for (int o=32;o;o>>=1) sum += __shfl_xor(sum, o, 64);
    if (lane == 0) reds[wid] = sum;
    __syncthreads();
    sum = reds[0];
    #pragma unroll
    for (int w2=1;w2<8;++w2) sum += reds[w2];
    float a = e / sum;
    accm += 0.25f * a;
    if (t == L-1) g_a511[h*L + u] = a;
  }
  out[1 + t*L + u] = accm;
}

// PV for row 511 only + output projection -> mol_emb
__global__ __launch_bounds__(256) void head_kernel(const float* __restrict__ ow, const float* __restrict__ ob){
  __shared__ float ash[4*L];
  __shared__ float osh[E];
  const int tid = threadIdx.x;
  for (int i=tid; i<4*L; i+=256) ash[i] = g_a511[i];
  __syncthreads();
  const int h = tid >> 6, d = tid & 63;
  float o = 0.f;
  const float* vp = g_qkv + 2*E + h*64 + d;
  for (int uu=0; uu<L; ++uu) o += ash[h*L + uu]*vp[uu*3*E];
  osh[tid] = o;
  __syncthreads();
  float m = ob[tid];
  const float* w = ow + tid*E;
  #pragma unroll 8
  for (int c2=0;c2<E;++c2) m += osh[c2]*w[c2];
  g_molemb[tid] = m;
}

// ---------------- final MLP ----------------
__global__ __launch_bounds__(640) void mlp_kernel(const float* __restrict__ smiles,
    const float* __restrict__ w1, const float* __restrict__ b1,
    const float* __restrict__ w2, const float* __restrict__ b2,
    const float* __restrict__ w3, const float* __restrict__ b3,
    const float* __restrict__ w4, const float* __restrict__ b4,
    float* __restrict__ out){
  __shared__ float f_sh[1152];
  __shared__ float a1[576];
  __shared__ float a2[256];
  __shared__ float a3[64];
  const int tid = threadIdx.x;
  if (tid < 256) f_sh[tid] = g_hg[tid];
  else if (tid < 512) f_sh[tid] = g_molemb[tid-256];
  if (tid < 638) f_sh[512 + tid] = smiles[tid];
  __syncthreads();
  if (tid < 575){
    float acc = b1[tid];
    const float2* w = (const float2*)(w1 + tid*1150);
    #pragma unroll 5
    for (int k=0;k<575;++k){ float2 wv = w[k]; acc += f_sh[2*k]*wv.x + f_sh[2*k+1]*wv.y; }
    a1[tid] = fmaxf(acc, 0.f);
  }
  __syncthreads();
  if (tid < 256){
    float acc = b2[tid];
    const float* w = w2 + tid*575;
    #pragma unroll 5
    for (int k=0;k<575;++k) acc += a1[k]*w[k];
    a2[tid] = fmaxf(acc, 0.f);
  }
  __syncthreads();
  if (tid < 64){
    float acc = b3[tid];
    const float* w = w3 + tid*256;
    #pragma unroll 8
    for (int k=0;k<256;++k) acc += a2[k]*w[k];
    a3[tid] = fmaxf(acc, 0.f);
  }
  __syncthreads();
  if (tid == 0){
    float acc = b4[0];
    #pragma unroll
    for (int k=0;k<64;++k) acc += a3[k]*w4[k];
    out[0] = acc;
  }
}

// ---------------- launch ----------------
extern "C" void kernel_launch(void* const* d_in, const int* in_sizes, int n_in,
                              void* d_out, int out_size, void* d_ws, size_t ws_size,
                              hipStream_t stream){
  (void)in_sizes; (void)n_in; (void)out_size; (void)d_ws; (void)ws_size;
  const float* g_mol   = (const float*)d_in[0];
  const float* feat    = (const float*)d_in[1];
  const float* smiles  = (const float*)d_in[2];
  const float* l0fWih  = (const float*)d_in[3];
  const float* l0fWhh  = (const float*)d_in[4];
  const float* l0fbih  = (const float*)d_in[5];
  const float* l0fbhh  = (const float*)d_in[6];
  const float* l0bWih  = (const float*)d_in[7];
  const float* l0bWhh  = (const float*)d_in[8];
  const float* l0bbih  = (const float*)d_in[9];
  const float* l0bbhh  = (const float*)d_in[10];
  const float* l1fWih  = (const float*)d_in[11];
  const float* l1fWhh  = (const float*)d_in[12];
  const float* l1fbih  = (const float*)d_in[13];
  const float* l1fbhh  = (const float*)d_in[14];
  const float* l1bWih  = (const float*)d_in[15];
  const float* l1bWhh  = (const float*)d_in[16];
  const float* l1bbih  = (const float*)d_in[17];
  const float* l1bbhh  = (const float*)d_in[18];
  const float* fcw     = (const float*)d_in[19];
  const float* fcb     = (const float*)d_in[20];
  const float* inw     = (const float*)d_in[21];
  const float* inb     = (const float*)d_in[22];
  const float* ow      = (const float*)d_in[23];
  const float* ob      = (const float*)d_in[24];
  const float* gc1w    = (const float*)d_in[25];
  const float* gc1b    = (const float*)d_in[26];
  const float* gc2w    = (const float*)d_in[27];
  const float* gc2b    = (const float*)d_in[28];
  const float* w1      = (const float*)d_in[29];
  const float* b1      = (const float*)d_in[30];
  const float* w2      = (const float*)d_in[31];
  const float* b2      = (const float*)d_in[32];
  const float* w3      = (const float*)d_in[33];
  const float* b3      = (const float*)d_in[34];
  const float* w4      = (const float*)d_in[35];
  const float* b4      = (const float*)d_in[36];
  const int*   src     = (const int*)d_in[37];
  const int*   dst     = (const int*)d_in[38];
  float* out = (float*)d_out;

  // GCN branch
  zero_kernel<<<196, 256, 0, stream>>>();
  hist_kernel<<<(NE+255)/256, 256, 0, stream>>>(src, dst);
  scan_kernel<<<1, 1024, 0, stream>>>();
  fill_kernel<<<(NE+255)/256, 256, 0, stream>>>(src, dst);
  agg_kernel<<<NN, 64, 0, stream>>>(feat);
  gemm1_kernel<<<NN/8, 256, 0, stream>>>(gc1w, gc1b);
  wsum_kernel<<<512, 128, 0, stream>>>();
  hg_kernel<<<1, 256, 0, stream>>>(gc2w, gc2b);

  // BiLSTM chain
  xg0_kernel<<<dim3(L,2), 512, 0, stream>>>(g_mol, l0fWih, l0fbih, l0fbhh, l0bWih, l0bbih, l0bbhh);
  lstm_kernel<<<2, 512, 0, stream>>>(l0fWhh, l0bWhh, 0);
  xg1_kernel<<<dim3(L,2), 512, 0, stream>>>(l1fWih, l1fbih, l1fbhh, l1bWih, l1bbih, l1bbhh);
  lstm_kernel<<<2, 512, 0, stream>>>(l1fWhh, l1bWhh, 1);

  // attention path
  proj_kernel<<<L, 256, 0, stream>>>(fcw, fcb);
  qkv_kernel<<<L, 256, 0, stream>>>(inw, inb);
  ktrans_kernel<<<L, 256, 0, stream>>>();
  attn_kernel<<<L, 512, 0, stream>>>(out);
  head_kernel<<<1, 256, 0, stream>>>(ow, ob);

  // final MLP
  mlp_kernel<<<1, 640, 0, stream>>>(smiles, w1, b1, w2, b2, w3, b3, w4, b4, out);
}

// Round 7
// 1613.839 us; speedup vs baseline: 1.1542x; 1.1542x over previous
//
#include <hip/hip_runtime.h>
#include <hip/hip_bf16.h>

#define L 512
#define H 128
#define E 256
#define NN 50000
#define NE 600000

// ---------------- static device scratch ----------------
__device__ float g_xg[4][L*512];     // [l0f,l0b,l1f,l1b] : xg incl. bih+bhh
__device__ float g_hs[4][L*H];       // hidden outputs per dir-layer
__device__ float g_proj[L*E];
__device__ float g_qkv[L*3*E];
__device__ float g_kmat[E*L];        // kmat[h*64+d][u]
__device__ float g_vmat[E*L];        // vmat[h*64+d][u]
__device__ float g_a511[4*L];
__device__ float g_molemb[E];
__device__ float g_ssum[H];
__device__ float g_hg[E];
__device__ float g_agg[NN*H];
__device__ int   g_cnt_dst[NN];
__device__ int   g_cnt_src[NN];
__device__ int   g_offs[NN+1];
__device__ int   g_cursor[NN];
__device__ int   g_eidx[NE];

__device__ __forceinline__ float sigm(float x){ return 1.f/(1.f+__expf(-x)); }
__device__ __forceinline__ float tanh_f(float x){ float e=__expf(2.f*x); return 1.f - 2.f/(e+1.f); }

// raw barrier: waits LDS only, leaves global loads in flight (no vmcnt drain)
__device__ __forceinline__ void bar_lds(){
  asm volatile("s_waitcnt lgkmcnt(0)" ::: "memory");
  __builtin_amdgcn_s_barrier();
  __builtin_amdgcn_sched_barrier(0);
}

// ---------------- GCN ----------------
__global__ void zero_kernel(){
  int i = blockIdx.x*blockDim.x + threadIdx.x;
  if (i < NN){ g_cnt_dst[i]=0; g_cnt_src[i]=0; }
  if (i < H) g_ssum[i]=0.f;
}

__global__ void hist_kernel(const int* __restrict__ src, const int* __restrict__ dst){
  int i = blockIdx.x*blockDim.x + threadIdx.x;
  if (i < NE){
    atomicAdd(&g_cnt_dst[dst[i]], 1);
    atomicAdd(&g_cnt_src[src[i]], 1);
  }
}

__global__ __launch_bounds__(1024) void scan_kernel(){
  __shared__ int part[1024];
  const int t = threadIdx.x;
  const int CH = 49;
  const int base = t*CH;
  int s = 0;
  for (int i=0;i<CH;i++){ int v=base+i; if (v<NN) s += g_cnt_dst[v]; }
  part[t] = s;
  __syncthreads();
  for (int off=1; off<1024; off<<=1){
    int v = part[t];
    if (t >= off) v += part[t-off];
    __syncthreads();
    part[t] = v;
    __syncthreads();
  }
  int run = part[t] - s;
  for (int i=0;i<CH;i++){
    int v = base+i;
    if (v < NN){ g_offs[v]=run; g_cursor[v]=run; run += g_cnt_dst[v]; }
  }
  if (t == 1023) g_offs[NN] = part[1023];
}

__global__ void fill_kernel(const int* __restrict__ src, const int* __restrict__ dst){
  int i = blockIdx.x*blockDim.x + threadIdx.x;
  if (i < NE){
    int p = atomicAdd(&g_cursor[dst[i]], 1);
    g_eidx[p] = src[i];
  }
}

__global__ __launch_bounds__(64) void agg_kernel(const float* __restrict__ feat){
  const int v = blockIdx.x;
  const int t = threadIdx.x;
  const int s = g_offs[v], e = g_offs[v+1];
  float2 acc = make_float2(0.f, 0.f);
  for (int j=s; j<e; ++j){
    const int sv = g_eidx[j];
    float2 x = ((const float2*)(feat + sv*H))[t];
    acc.x += x.x; acc.y += x.y;
  }
  ((float2*)(g_agg + v*H))[t] = acc;
}

__global__ __launch_bounds__(256) void gemm1_kernel(const float* __restrict__ W, const float* __restrict__ b){
  __shared__ __align__(16) float ash[8*H];
  const int tid = threadIdx.x;
  const int base = blockIdx.x * 8;
  for (int i=tid; i<8*H; i+=256) ash[i] = g_agg[base*H + i];
  __syncthreads();
  const int r  = tid >> 5;
  const int j4 = tid & 31;
  float4 acc = ((const float4*)b)[j4];
  const float* arow = ash + r*H;
  const float4* W4 = (const float4*)W;
  #pragma unroll 8
  for (int k=0;k<H;++k){
    float4 wv = W4[k*32 + j4];
    float av = arow[k];
    acc.x += av*wv.x; acc.y += av*wv.y; acc.z += av*wv.z; acc.w += av*wv.w;
  }
  float4 o = make_float4(fmaxf(acc.x,0.f), fmaxf(acc.y,0.f), fmaxf(acc.z,0.f), fmaxf(acc.w,0.f));
  ((float4*)(g_agg + (base + r)*H))[j4] = o;
}

__global__ __launch_bounds__(128) void wsum_kernel(){
  const int c = threadIdx.x;
  const int v0 = blockIdx.x * 98;
  const int v1 = (v0+98 < NN) ? v0+98 : NN;
  float acc = 0.f;
  for (int v=v0; v<v1; ++v)
    acc += (float)g_cnt_src[v] * g_agg[v*H + c];
  atomicAdd(&g_ssum[c], acc);
}

__global__ __launch_bounds__(256) void hg_kernel(const float* __restrict__ W2, const float* __restrict__ b2){
  __shared__ float ssh[H];
  const int j = threadIdx.x;
  if (j < H) ssh[j] = g_ssum[j] * (1.f/(float)NN);
  __syncthreads();
  float acc = b2[j];
  #pragma unroll 8
  for (int k=0;k<H;++k) acc += ssh[k]*W2[k*E + j];
  g_hg[j] = acc;
}

// ---------------- BiLSTM ----------------
__global__ __launch_bounds__(512) void xg0_kernel(const float* __restrict__ x,
    const float* __restrict__ Wf, const float* __restrict__ bif, const float* __restrict__ bhf,
    const float* __restrict__ Wb, const float* __restrict__ bib, const float* __restrict__ bhb){
  const int t = blockIdx.x, dir = blockIdx.y, j = threadIdx.x;
  __shared__ float xr[14];
  if (j < 14) xr[j] = x[t*14 + j];
  __syncthreads();
  const float* W = dir ? Wb : Wf;
  float acc = dir ? (bib[j]+bhb[j]) : (bif[j]+bhf[j]);
  #pragma unroll
  for (int k=0;k<14;++k) acc += xr[k]*W[j*14 + k];
  g_xg[dir][t*512 + j] = acc;
}

// layer1 xg, 4 timesteps per block: y[4][256] staged, thread j does 4 dots
__global__ __launch_bounds__(512) void xg1_kernel(
    const float* __restrict__ Wf, const float* __restrict__ bif, const float* __restrict__ bhf,
    const float* __restrict__ Wb, const float* __restrict__ bib, const float* __restrict__ bhb){
  const int t0 = blockIdx.x*4, dir = blockIdx.y, j = threadIdx.x;
  __shared__ __align__(16) float y[4][E];
  for (int idx=j; idx<4*E; idx+=512){
    int tl = idx >> 8, c = idx & 255;
    y[tl][c] = (c < H) ? g_hs[0][(t0+tl)*H + c] : g_hs[1][(t0+tl)*H + (c-H)];
  }
  __syncthreads();
  const float* W = dir ? Wb : Wf;
  float b = dir ? (bib[j]+bhb[j]) : (bif[j]+bhf[j]);
  float a0=b, a1=b, a2=b, a3=b;
  const float4* w4 = (const float4*)(W + j*E);
  #pragma unroll 4
  for (int k4=0;k4<64;++k4){
    float4 w = w4[k4];
    float4 p0=((const float4*)y[0])[k4], p1=((const float4*)y[1])[k4];
    float4 p2=((const float4*)y[2])[k4], p3=((const float4*)y[3])[k4];
    a0 += w.x*p0.x + w.y*p0.y + w.z*p0.z + w.w*p0.w;
    a1 += w.x*p1.x + w.y*p1.y + w.z*p1.z + w.w*p1.w;
    a2 += w.x*p2.x + w.y*p2.y + w.z*p2.z + w.w*p2.w;
    a3 += w.x*p3.x + w.y*p3.y + w.z*p3.z + w.w*p3.w;
  }
  float* o = g_xg[2+dir];
  o[(t0+0)*512 + j] = a0; o[(t0+1)*512 + j] = a1;
  o[(t0+2)*512 + j] = a2; o[(t0+3)*512 + j] = a3;
}

// LSTM v2: K-quarter split. thread t: unit u=t&127, quarter q=t>>7.
// Per step: wave broadcasts only its 32-float h-slice (8 b128 vs 32).
__global__ __launch_bounds__(512) void lstm_kernel(const float* __restrict__ WhhF,
                                                   const float* __restrict__ WhhB, int layer){
  const int dir = blockIdx.x;
  const float* __restrict__ Whh = dir ? WhhB : WhhF;
  const float* __restrict__ xg  = g_xg[layer*2 + dir];
  float* __restrict__ hs        = g_hs[layer*2 + dir];
  const int t = threadIdx.x;
  const int u = t & 127, q = t >> 7;
  float wreg[4][32];
  #pragma unroll
  for (int g=0; g<4; ++g){
    const float4* W4 = (const float4*)(Whh + (g*128+u)*H + q*32);
    #pragma unroll
    for (int k4=0;k4<8;++k4){
      float4 v = W4[k4];
      wreg[g][4*k4]=v.x; wreg[g][4*k4+1]=v.y; wreg[g][4*k4+2]=v.z; wreg[g][4*k4+3]=v.w;
    }
  }
  __shared__ __align__(16) float hsm[H];
  __shared__ float part[4*512];          // [q][g*128+u]
  if (t < H) hsm[t] = 0.f;
  float c = 0.f;
  float xgi=0.f, xgf=0.f, xgg=0.f, xgo=0.f;
  {
    int tt0 = dir ? (L-1) : 0;
    if (t < 128){
      xgi = xg[tt0*512 + u];       xgf = xg[tt0*512 + 128 + u];
      xgg = xg[tt0*512 + 256 + u]; xgo = xg[tt0*512 + 384 + u];
    }
  }
  __syncthreads();
  for (int s=0; s<L; ++s){
    const int tt = dir ? (L-1-s) : s;
    // phase 1: partial dots over this thread's k-quarter
    float hq[32];
    const float4* h4 = (const float4*)(hsm + q*32);
    #pragma unroll
    for (int k4=0;k4<8;++k4){
      float4 v = h4[k4];
      hq[4*k4]=v.x; hq[4*k4+1]=v.y; hq[4*k4+2]=v.z; hq[4*k4+3]=v.w;
    }
    float a0=0.f, a1=0.f, a2=0.f, a3=0.f;
    #pragma unroll
    for (int k=0;k<32;++k){
      float hv = hq[k];
      a0 += wreg[0][k]*hv; a1 += wreg[1][k]*hv;
      a2 += wreg[2][k]*hv; a3 += wreg[3][k]*hv;
    }
    part[q*512 + u]       = a0;
    part[q*512 + 128 + u] = a1;
    part[q*512 + 256 + u] = a2;
    part[q*512 + 384 + u] = a3;
    bar_lds();
    // phase 2: reduce + activate + state update (threads 0..127 = waves 0,1)
    if (t < 128){
      float gi = xgi + part[u]       + part[512+u]       + part[1024+u]       + part[1536+u];
      float gf = xgf + part[128+u]   + part[640+u]       + part[1152+u]       + part[1664+u];
      float gg = xgg + part[256+u]   + part[768+u]       + part[1280+u]       + part[1792+u];
      float go = xgo + part[384+u]   + part[896+u]       + part[1408+u]       + part[1920+u];
      int ttn = dir ? (L-2-s) : (s+1);
      ttn = ttn < 0 ? 0 : (ttn > L-1 ? L-1 : ttn);
      xgi = xg[ttn*512 + u];       xgf = xg[ttn*512 + 128 + u];
      xgg = xg[ttn*512 + 256 + u]; xgo = xg[ttn*512 + 384 + u];
      gi = sigm(gi); gf = sigm(gf); gg = tanh_f(gg); go = sigm(go);
      c = gf*c + gi*gg;
      float hn = go*tanh_f(c);
      hsm[u] = hn;
      hs[tt*H + u] = hn;
    }
    bar_lds();
  }
}

// ---------------- attention path ----------------
// proj, 4 timesteps per block
__global__ __launch_bounds__(256) void proj_kernel(const float* __restrict__ fcw, const float* __restrict__ fcb){
  const int t0 = blockIdx.x*4, j = threadIdx.x;
  __shared__ __align__(16) float y[4][E];
  for (int idx=j; idx<4*E; idx+=256){
    int tl = idx >> 8, c = idx & 255;
    y[tl][c] = (c < H) ? g_hs[2][(t0+tl)*H + c] : g_hs[3][(t0+tl)*H + (c-H)];
  }
  __syncthreads();
  float b = fcb[j];
  float a0=b, a1=b, a2=b, a3=b;
  const float4* w4 = (const float4*)(fcw + j*E);
  #pragma unroll 4
  for (int k4=0;k4<64;++k4){
    float4 w = w4[k4];
    float4 p0=((const float4*)y[0])[k4], p1=((const float4*)y[1])[k4];
    float4 p2=((const float4*)y[2])[k4], p3=((const float4*)y[3])[k4];
    a0 += w.x*p0.x + w.y*p0.y + w.z*p0.z + w.w*p0.w;
    a1 += w.x*p1.x + w.y*p1.y + w.z*p1.z + w.w*p1.w;
    a2 += w.x*p2.x + w.y*p2.y + w.z*p2.z + w.w*p2.w;
    a3 += w.x*p3.x + w.y*p3.y + w.z*p3.z + w.w*p3.w;
  }
  g_proj[(t0+0)*E + j] = a0; g_proj[(t0+1)*E + j] = a1;
  g_proj[(t0+2)*E + j] = a2; g_proj[(t0+3)*E + j] = a3;
}

// qkv, 4 timesteps per block
__global__ __launch_bounds__(256) void qkv_kernel(const float* __restrict__ inw, const float* __restrict__ inb){
  const int t0 = blockIdx.x*4, tid = threadIdx.x;
  __shared__ __align__(16) float pr[4][E];
  for (int idx=tid; idx<4*E; idx+=256) pr[idx>>8][idx&255] = g_proj[t0*E + idx];
  __syncthreads();
  for (int r=0;r<3;++r){
    const int j = r*E + tid;
    float b = inb[j];
    float a0=b, a1=b, a2=b, a3=b;
    const float4* w4 = (const float4*)(inw + j*E);
    #pragma unroll 4
    for (int k4=0;k4<64;++k4){
      float4 w = w4[k4];
      float4 p0=((const float4*)pr[0])[k4], p1=((const float4*)pr[1])[k4];
      float4 p2=((const float4*)pr[2])[k4], p3=((const float4*)pr[3])[k4];
      a0 += w.x*p0.x + w.y*p0.y + w.z*p0.z + w.w*p0.w;
      a1 += w.x*p1.x + w.y*p1.y + w.z*p1.z + w.w*p1.w;
      a2 += w.x*p2.x + w.y*p2.y + w.z*p2.z + w.w*p2.w;
      a3 += w.x*p3.x + w.y*p3.y + w.z*p3.z + w.w*p3.w;
    }
    g_qkv[(t0+0)*768 + j] = a0; g_qkv[(t0+1)*768 + j] = a1;
    g_qkv[(t0+2)*768 + j] = a2; g_qkv[(t0+3)*768 + j] = a3;
  }
}

// tiled transpose of K and V: kmat/vmat[c][u], coalesced both sides
__global__ __launch_bounds__(256) void ktrans_kernel(){
  __shared__ float tK[32][33];
  __shared__ float tV[32][33];
  const int bu = blockIdx.x, bc = blockIdx.y;
  const int tx = threadIdx.x & 31, ty = threadIdx.x >> 5;
  #pragma unroll
  for (int r=0; r<32; r+=8){
    int uu = bu*32 + ty + r;
    tK[ty+r][tx] = g_qkv[uu*768 + 256 + bc*32 + tx];
    tV[ty+r][tx] = g_qkv[uu*768 + 512 + bc*32 + tx];
  }
  __syncthreads();
  #pragma unroll
  for (int r=0; r<32; r+=8){
    int cc = bc*32 + ty + r;
    g_kmat[cc*512 + bu*32 + tx] = tK[tx][ty+r];
    g_vmat[cc*512 + bu*32 + tx] = tV[tx][ty+r];
  }
}

__global__ __launch_bounds__(512) void attn_kernel(float* __restrict__ out){
  const int t = blockIdx.x, u = threadIdx.x;
  const int lane = u & 63, wid = u >> 6;
  __shared__ float qsh[64];
  __shared__ float redm[8], reds[8];
  float accm = 0.f;
  for (int h=0; h<4; ++h){
    __syncthreads();
    if (u < 64) qsh[u] = g_qkv[t*3*E + h*64 + u];
    __syncthreads();
    const float* km = g_kmat + h*64*L + u;
    float s = 0.f;
    #pragma unroll 8
    for (int d=0; d<64; ++d) s += qsh[d]*km[d*L];
    s *= 0.125f;
    float m = s;
    for (int o=32;o;o>>=1) m = fmaxf(m, __shfl_xor(m, o, 64));
    if (lane == 0) redm[wid] = m;
    __syncthreads();
    m = redm[0];
    #pragma unroll
    for (int w2=1;w2<8;++w2) m = fmaxf(m, redm[w2]);
    float e = __expf(s - m);
    float sum = e;
    for (int o=32;o;o>>=1) sum += __shfl_xor(sum, o, 64);
    if (lane == 0) reds[wid] = sum;
    __syncthreads();
    sum = reds[0];
    #pragma unroll
    for (int w2=1;w2<8;++w2) sum += reds[w2];
    float a = e / sum;
    accm += 0.25f * a;
    if (t == L-1) g_a511[h*L + u] = a;
  }
  out[1 + t*L + u] = accm;
}

// PV row 511 via vmat rows (sequential float4 per thread) + out projection
__global__ __launch_bounds__(256) void head_kernel(const float* __restrict__ ow, const float* __restrict__ ob){
  __shared__ __align__(16) float ash[4*L];
  __shared__ float osh[E];
  const int tid = threadIdx.x;
  for (int i=tid; i<4*L; i+=256) ash[i] = g_a511[i];
  __syncthreads();
  const int h = tid >> 6, d = tid & 63;
  float o = 0.f;
  const float4* v4 = (const float4*)(g_vmat + (h*64+d)*L);
  const float4* a4 = (const float4*)(ash + h*L);
  #pragma unroll 4
  for (int uu=0; uu<128; ++uu){
    float4 v = v4[uu], a = a4[uu];
    o += a.x*v.x + a.y*v.y + a.z*v.z + a.w*v.w;
  }
  osh[tid] = o;
  __syncthreads();
  float m = ob[tid];
  const float* w = ow + tid*E;
  #pragma unroll 8
  for (int c2=0;c2<E;++c2) m += osh[c2]*w[c2];
  g_molemb[tid] = m;
}

// ---------------- final MLP ----------------
__global__ __launch_bounds__(640) void mlp_kernel(const float* __restrict__ smiles,
    const float* __restrict__ w1, const float* __restrict__ b1,
    const float* __restrict__ w2, const float* __restrict__ b2,
    const float* __restrict__ w3, const float* __restrict__ b3,
    const float* __restrict__ w4, const float* __restrict__ b4,
    float* __restrict__ out){
  __shared__ float f_sh[1152];
  __shared__ float a1[576];
  __shared__ float a2[256];
  __shared__ float a3[64];
  const int tid = threadIdx.x;
  if (tid < 256) f_sh[tid] = g_hg[tid];
  else if (tid < 512) f_sh[tid] = g_molemb[tid-256];
  if (tid < 638) f_sh[512 + tid] = smiles[tid];
  __syncthreads();
  if (tid < 575){
    float acc = b1[tid];
    const float2* w = (const float2*)(w1 + tid*1150);
    #pragma unroll 5
    for (int k=0;k<575;++k){ float2 wv = w[k]; acc += f_sh[2*k]*wv.x + f_sh[2*k+1]*wv.y; }
    a1[tid] = fmaxf(acc, 0.f);
  }
  __syncthreads();
  if (tid < 256){
    float acc = b2[tid];
    const float* w = w2 + tid*575;
    #pragma unroll 5
    for (int k=0;k<575;++k) acc += a1[k]*w[k];
    a2[tid] = fmaxf(acc, 0.f);
  }
  __syncthreads();
  if (tid < 64){
    float acc = b3[tid];
    const float* w = w3 + tid*256;
    #pragma unroll 8
    for (int k=0;k<256;++k) acc += a2[k]*w[k];
    a3[tid] = fmaxf(acc, 0.f);
  }
  __syncthreads();
  if (tid == 0){
    float acc = b4[0];
    #pragma unroll
    for (int k=0;k<64;++k) acc += a3[k]*w4[k];
    out[0] = acc;
  }
}

// ---------------- launch ----------------
extern "C" void kernel_launch(void* const* d_in, const int* in_sizes, int n_in,
                              void* d_out, int out_size, void* d_ws, size_t ws_size,
                              hipStream_t stream){
  (void)in_sizes; (void)n_in; (void)out_size; (void)d_ws; (void)ws_size;
  const float* g_mol   = (const float*)d_in[0];
  const float* feat    = (const float*)d_in[1];
  const float* smiles  = (const float*)d_in[2];
  const float* l0fWih  = (const float*)d_in[3];
  const float* l0fWhh  = (const float*)d_in[4];
  const float* l0fbih  = (const float*)d_in[5];
  const float* l0fbhh  = (const float*)d_in[6];
  const float* l0bWih  = (const float*)d_in[7];
  const float* l0bWhh  = (const float*)d_in[8];
  const float* l0bbih  = (const float*)d_in[9];
  const float* l0bbhh  = (const float*)d_in[10];
  const float* l1fWih  = (const float*)d_in[11];
  const float* l1fWhh  = (const float*)d_in[12];
  const float* l1fbih  = (const float*)d_in[13];
  const float* l1fbhh  = (const float*)d_in[14];
  const float* l1bWih  = (const float*)d_in[15];
  const float* l1bWhh  = (const float*)d_in[16];
  const float* l1bbih  = (const float*)d_in[17];
  const float* l1bbhh  = (const float*)d_in[18];
  const float* fcw     = (const float*)d_in[19];
  const float* fcb     = (const float*)d_in[20];
  const float* inw     = (const float*)d_in[21];
  const float* inb     = (const float*)d_in[22];
  const float* ow      = (const float*)d_in[23];
  const float* ob      = (const float*)d_in[24];
  const float* gc1w    = (const float*)d_in[25];
  const float* gc1b    = (const float*)d_in[26];
  const float* gc2w    = (const float*)d_in[27];
  const float* gc2b    = (const float*)d_in[28];
  const float* w1      = (const float*)d_in[29];
  const float* b1      = (const float*)d_in[30];
  const float* w2      = (const float*)d_in[31];
  const float* b2      = (const float*)d_in[32];
  const float* w3      = (const float*)d_in[33];
  const float* b3      = (const float*)d_in[34];
  const float* w4      = (const float*)d_in[35];
  const float* b4      = (const float*)d_in[36];
  const int*   src     = (const int*)d_in[37];
  const int*   dst     = (const int*)d_in[38];
  float* out = (float*)d_out;

  // GCN branch
  zero_kernel<<<196, 256, 0, stream>>>();
  hist_kernel<<<(NE+255)/256, 256, 0, stream>>>(src, dst);
  scan_kernel<<<1, 1024, 0, stream>>>();
  fill_kernel<<<(NE+255)/256, 256, 0, stream>>>(src, dst);
  agg_kernel<<<NN, 64, 0, stream>>>(feat);
  gemm1_kernel<<<NN/8, 256, 0, stream>>>(gc1w, gc1b);
  wsum_kernel<<<512, 128, 0, stream>>>();
  hg_kernel<<<1, 256, 0, stream>>>(gc2w, gc2b);

  // BiLSTM chain
  xg0_kernel<<<dim3(L,2), 512, 0, stream>>>(g_mol, l0fWih, l0fbih, l0fbhh, l0bWih, l0bbih, l0bbhh);
  lstm_kernel<<<2, 512, 0, stream>>>(l0fWhh, l0bWhh, 0);
  xg1_kernel<<<dim3(128,2), 512, 0, stream>>>(l1fWih, l1fbih, l1fbhh, l1bWih, l1bbih, l1bbhh);
  lstm_kernel<<<2, 512, 0, stream>>>(l1fWhh, l1bWhh, 1);

  // attention path
  proj_kernel<<<128, 256, 0, stream>>>(fcw, fcb);
  qkv_kernel<<<128, 256, 0, stream>>>(inw, inb);
  ktrans_kernel<<<dim3(16,8), 256, 0, stream>>>();
  attn_kernel<<<L, 512, 0, stream>>>(out);
  head_kernel<<<1, 256, 0, stream>>>(ow, ob);

  // final MLP
  mlp_kernel<<<1, 640, 0, stream>>>(smiles, w1, b1, w2, b2, w3, b3, w4, b4, out);
}

// Round 14
// 1596.972 us; speedup vs baseline: 1.1664x; 1.0106x over previous
//
#include <hip/hip_runtime.h>
#include <hip/hip_bf16.h>

#define L 512
#define H 128
#define E 256
#define NN 50000
#define NE 600000

// ---------------- static device scratch ----------------
__device__ float g_xg[4][L*512];     // [l0f,l0b,l1f,l1b] : xg incl. bih+bhh
__device__ float g_hs[4][L*H];       // hidden outputs per dir-layer
__device__ float g_proj[L*E];
__device__ float g_qkv[L*3*E];
__device__ float g_kmat[E*L];        // kmat[h*64+d][u]
__device__ float g_vmat[E*L];        // vmat[h*64+d][u]
__device__ float g_a511[4*L];
__device__ float g_molemb[E];
__device__ float g_ssum[H];
__device__ float g_hg[E];
__device__ float g_agg[NN*H];
__device__ int   g_cnt_dst[NN];
__device__ int   g_cnt_src[NN];
__device__ int   g_offs[NN+1];
__device__ int   g_cursor[NN];
__device__ int   g_eidx[NE];

__device__ __forceinline__ float sigm(float x){ return 1.f/(1.f+__expf(-x)); }
__device__ __forceinline__ float tanh_f(float x){ float e=__expf(2.f*x); return 1.f - 2.f/(e+1.f); }

// raw barrier: waits LDS only, leaves global loads in flight (no vmcnt drain)
__device__ __forceinline__ void bar_lds(){
  asm volatile("s_waitcnt lgkmcnt(0)" ::: "memory");
  __builtin_amdgcn_s_barrier();
  __builtin_amdgcn_sched_barrier(0);
}

// ---------------- GCN ----------------
__global__ void zero_kernel(){
  int i = blockIdx.x*blockDim.x + threadIdx.x;
  if (i < NN){ g_cnt_dst[i]=0; g_cnt_src[i]=0; }
  if (i < H) g_ssum[i]=0.f;
}

__global__ void hist_kernel(const int* __restrict__ src, const int* __restrict__ dst){
  int i = blockIdx.x*blockDim.x + threadIdx.x;
  if (i < NE){
    atomicAdd(&g_cnt_dst[dst[i]], 1);
    atomicAdd(&g_cnt_src[src[i]], 1);
  }
}

__global__ __launch_bounds__(1024) void scan_kernel(){
  __shared__ int part[1024];
  const int t = threadIdx.x;
  const int CH = 49;
  const int base = t*CH;
  int s = 0;
  for (int i=0;i<CH;i++){ int v=base+i; if (v<NN) s += g_cnt_dst[v]; }
  part[t] = s;
  __syncthreads();
  for (int off=1; off<1024; off<<=1){
    int v = part[t];
    if (t >= off) v += part[t-off];
    __syncthreads();
    part[t] = v;
    __syncthreads();
  }
  int run = part[t] - s;
  for (int i=0;i<CH;i++){
    int v = base+i;
    if (v < NN){ g_offs[v]=run; g_cursor[v]=run; run += g_cnt_dst[v]; }
  }
  if (t == 1023) g_offs[NN] = part[1023];
}

__global__ void fill_kernel(const int* __restrict__ src, const int* __restrict__ dst){
  int i = blockIdx.x*blockDim.x + threadIdx.x;
  if (i < NE){
    int p = atomicAdd(&g_cursor[dst[i]], 1);
    g_eidx[p] = src[i];
  }
}

__global__ __launch_bounds__(64) void agg_kernel(const float* __restrict__ feat){
  const int v = blockIdx.x;
  const int t = threadIdx.x;
  const int s = g_offs[v], e = g_offs[v+1];
  float2 acc = make_float2(0.f, 0.f);
  for (int j=s; j<e; ++j){
    const int sv = g_eidx[j];
    float2 x = ((const float2*)(feat + sv*H))[t];
    acc.x += x.x; acc.y += x.y;
  }
  ((float2*)(g_agg + v*H))[t] = acc;
}

__global__ __launch_bounds__(256) void gemm1_kernel(const float* __restrict__ W, const float* __restrict__ b){
  __shared__ __align__(16) float ash[8*H];
  const int tid = threadIdx.x;
  const int base = blockIdx.x * 8;
  for (int i=tid; i<8*H; i+=256) ash[i] = g_agg[base*H + i];
  __syncthreads();
  const int r  = tid >> 5;
  const int j4 = tid & 31;
  float4 acc = ((const float4*)b)[j4];
  const float* arow = ash + r*H;
  const float4* W4 = (const float4*)W;
  #pragma unroll 8
  for (int k=0;k<H;++k){
    float4 wv = W4[k*32 + j4];
    float av = arow[k];
    acc.x += av*wv.x; acc.y += av*wv.y; acc.z += av*wv.z; acc.w += av*wv.w;
  }
  float4 o = make_float4(fmaxf(acc.x,0.f), fmaxf(acc.y,0.f), fmaxf(acc.z,0.f), fmaxf(acc.w,0.f));
  ((float4*)(g_agg + (base + r)*H))[j4] = o;
}

__global__ __launch_bounds__(128) void wsum_kernel(){
  const int c = threadIdx.x;
  const int v0 = blockIdx.x * 98;
  const int v1 = (v0+98 < NN) ? v0+98 : NN;
  float acc = 0.f;
  for (int v=v0; v<v1; ++v)
    acc += (float)g_cnt_src[v] * g_agg[v*H + c];
  atomicAdd(&g_ssum[c], acc);
}

__global__ __launch_bounds__(256) void hg_kernel(const float* __restrict__ W2, const float* __restrict__ b2){
  __shared__ float ssh[H];
  const int j = threadIdx.x;
  if (j < H) ssh[j] = g_ssum[j] * (1.f/(float)NN);
  __syncthreads();
  float acc = b2[j];
  #pragma unroll 8
  for (int k=0;k<H;++k) acc += ssh[k]*W2[k*E + j];
  g_hg[j] = acc;
}

// ---------------- BiLSTM ----------------
__global__ __launch_bounds__(512) void xg0_kernel(const float* __restrict__ x,
    const float* __restrict__ Wf, const float* __restrict__ bif, const float* __restrict__ bhf,
    const float* __restrict__ Wb, const float* __restrict__ bib, const float* __restrict__ bhb){
  const int t = blockIdx.x, dir = blockIdx.y, j = threadIdx.x;
  __shared__ float xr[14];
  if (j < 14) xr[j] = x[t*14 + j];
  __syncthreads();
  const float* W = dir ? Wb : Wf;
  float acc = dir ? (bib[j]+bhb[j]) : (bif[j]+bhf[j]);
  #pragma unroll
  for (int k=0;k<14;++k) acc += xr[k]*W[j*14 + k];
  g_xg[dir][t*512 + j] = acc;
}

// layer1 xg, 4 timesteps per block
__global__ __launch_bounds__(512) void xg1_kernel(
    const float* __restrict__ Wf, const float* __restrict__ bif, const float* __restrict__ bhf,
    const float* __restrict__ Wb, const float* __restrict__ bib, const float* __restrict__ bhb){
  const int t0 = blockIdx.x*4, dir = blockIdx.y, j = threadIdx.x;
  __shared__ __align__(16) float y[4][E];
  for (int idx=j; idx<4*E; idx+=512){
    int tl = idx >> 8, c = idx & 255;
    y[tl][c] = (c < H) ? g_hs[0][(t0+tl)*H + c] : g_hs[1][(t0+tl)*H + (c-H)];
  }
  __syncthreads();
  const float* W = dir ? Wb : Wf;
  float b = dir ? (bib[j]+bhb[j]) : (bif[j]+bhf[j]);
  float a0=b, a1=b, a2=b, a3=b;
  const float4* w4 = (const float4*)(W + j*E);
  #pragma unroll 4
  for (int k4=0;k4<64;++k4){
    float4 w = w4[k4];
    float4 p0=((const float4*)y[0])[k4], p1=((const float4*)y[1])[k4];
    float4 p2=((const float4*)y[2])[k4], p3=((const float4*)y[3])[k4];
    a0 += w.x*p0.x + w.y*p0.y + w.z*p0.z + w.w*p0.w;
    a1 += w.x*p1.x + w.y*p1.y + w.z*p1.z + w.w*p1.w;
    a2 += w.x*p2.x + w.y*p2.y + w.z*p2.z + w.w*p2.w;
    a3 += w.x*p3.x + w.y*p3.y + w.z*p3.z + w.w*p3.w;
  }
  float* o = g_xg[2+dir];
  o[(t0+0)*512 + j] = a0; o[(t0+1)*512 + j] = a1;
  o[(t0+2)*512 + j] = a2; o[(t0+3)*512 + j] = a3;
}

// LSTM v2 + launch_bounds: K-quarter split, 2-phase (verbatim round-7 PASS
// structure; ONLY change is __launch_bounds__(512,2) so wreg[4][32] stays in
// arch VGPRs instead of being AGPR-shunted at the default occupancy target).
__global__ __launch_bounds__(512, 2) void lstm_kernel(const float* __restrict__ WhhF,
                                                      const float* __restrict__ WhhB, int layer){
  const int dir = blockIdx.x;
  const float* __restrict__ Whh = dir ? WhhB : WhhF;
  const float* __restrict__ xg  = g_xg[layer*2 + dir];
  float* __restrict__ hs        = g_hs[layer*2 + dir];
  const int t = threadIdx.x;
  const int u = t & 127, q = t >> 7;
  float wreg[4][32];
  #pragma unroll
  for (int g=0; g<4; ++g){
    const float4* W4 = (const float4*)(Whh + (g*128+u)*H + q*32);
    #pragma unroll
    for (int k4=0;k4<8;++k4){
      float4 v = W4[k4];
      wreg[g][4*k4]=v.x; wreg[g][4*k4+1]=v.y; wreg[g][4*k4+2]=v.z; wreg[g][4*k4+3]=v.w;
    }
  }
  __shared__ __align__(16) float hsm[H];
  __shared__ float part[4*512];          // [q][g*128+u]
  if (t < H) hsm[t] = 0.f;
  float c = 0.f;
  float xgi=0.f, xgf=0.f, xgg=0.f, xgo=0.f;
  {
    int tt0 = dir ? (L-1) : 0;
    if (t < 128){
      xgi = xg[tt0*512 + u];       xgf = xg[tt0*512 + 128 + u];
      xgg = xg[tt0*512 + 256 + u]; xgo = xg[tt0*512 + 384 + u];
    }
  }
  __syncthreads();
  for (int s=0; s<L; ++s){
    const int tt = dir ? (L-1-s) : s;
    // phase 1: partial dots over this thread's k-quarter
    float hq[32];
    const float4* h4 = (const float4*)(hsm + q*32);
    #pragma unroll
    for (int k4=0;k4<8;++k4){
      float4 v = h4[k4];
      hq[4*k4]=v.x; hq[4*k4+1]=v.y; hq[4*k4+2]=v.z; hq[4*k4+3]=v.w;
    }
    float a0=0.f, a1=0.f, a2=0.f, a3=0.f;
    #pragma unroll
    for (int k=0;k<32;++k){
      float hv = hq[k];
      a0 += wreg[0][k]*hv; a1 += wreg[1][k]*hv;
      a2 += wreg[2][k]*hv; a3 += wreg[3][k]*hv;
    }
    part[q*512 + u]       = a0;
    part[q*512 + 128 + u] = a1;
    part[q*512 + 256 + u] = a2;
    part[q*512 + 384 + u] = a3;
    bar_lds();
    // phase 2: reduce + activate + state update (threads 0..127 = waves 0,1)
    if (t < 128){
      float gi = xgi + part[u]       + part[512+u]       + part[1024+u]       + part[1536+u];
      float gf = xgf + part[128+u]   + part[640+u]       + part[1152+u]       + part[1664+u];
      float gg = xgg + part[256+u]   + part[768+u]       + part[1280+u]       + part[1792+u];
      float go = xgo + part[384+u]   + part[896+u]       + part[1408+u]       + part[1920+u];
      int ttn = dir ? (L-2-s) : (s+1);
      ttn = ttn < 0 ? 0 : (ttn > L-1 ? L-1 : ttn);
      xgi = xg[ttn*512 + u];       xgf = xg[ttn*512 + 128 + u];
      xgg = xg[ttn*512 + 256 + u]; xgo = xg[ttn*512 + 384 + u];
      gi = sigm(gi); gf = sigm(gf); gg = tanh_f(gg); go = sigm(go);
      c = gf*c + gi*gg;
      float hn = go*tanh_f(c);
      hsm[u] = hn;
      hs[tt*H + u] = hn;
    }
    bar_lds();
  }
}

// ---------------- attention path ----------------
// proj, 4 timesteps per block
__global__ __launch_bounds__(256) void proj_kernel(const float* __restrict__ fcw, const float* __restrict__ fcb){
  const int t0 = blockIdx.x*4, j = threadIdx.x;
  __shared__ __align__(16) float y[4][E];
  for (int idx=j; idx<4*E; idx+=256){
    int tl = idx >> 8, c = idx & 255;
    y[tl][c] = (c < H) ? g_hs[2][(t0+tl)*H + c] : g_hs[3][(t0+tl)*H + (c-H)];
  }
  __syncthreads();
  float b = fcb[j];
  float a0=b, a1=b, a2=b, a3=b;
  const float4* w4 = (const float4*)(fcw + j*E);
  #pragma unroll 4
  for (int k4=0;k4<64;++k4){
    float4 w = w4[k4];
    float4 p0=((const float4*)y[0])[k4], p1=((const float4*)y[1])[k4];
    float4 p2=((const float4*)y[2])[k4], p3=((const float4*)y[3])[k4];
    a0 += w.x*p0.x + w.y*p0.y + w.z*p0.z + w.w*p0.w;
    a1 += w.x*p1.x + w.y*p1.y + w.z*p1.z + w.w*p1.w;
    a2 += w.x*p2.x + w.y*p2.y + w.z*p2.z + w.w*p2.w;
    a3 += w.x*p3.x + w.y*p3.y + w.z*p3.z + w.w*p3.w;
  }
  g_proj[(t0+0)*E + j] = a0; g_proj[(t0+1)*E + j] = a1;
  g_proj[(t0+2)*E + j] = a2; g_proj[(t0+3)*E + j] = a3;
}

// qkv, 4 timesteps per block
__global__ __launch_bounds__(256) void qkv_kernel(const float* __restrict__ inw, const float* __restrict__ inb){
  const int t0 = blockIdx.x*4, tid = threadIdx.x;
  __shared__ __align__(16) float pr[4][E];
  for (int idx=tid; idx<4*E; idx+=256) pr[idx>>8][idx&255] = g_proj[t0*E + idx];
  __syncthreads();
  for (int r=0;r<3;++r){
    const int j = r*E + tid;
    float b = inb[j];
    float a0=b, a1=b, a2=b, a3=b;
    const float4* w4 = (const float4*)(inw + j*E);
    #pragma unroll 4
    for (int k4=0;k4<64;++k4){
      float4 w = w4[k4];
      float4 p0=((const float4*)pr[0])[k4], p1=((const float4*)pr[1])[k4];
      float4 p2=((const float4*)pr[2])[k4], p3=((const float4*)pr[3])[k4];
      a0 += w.x*p0.x + w.y*p0.y + w.z*p0.z + w.w*p0.w;
      a1 += w.x*p1.x + w.y*p1.y + w.z*p1.z + w.w*p1.w;
      a2 += w.x*p2.x + w.y*p2.y + w.z*p2.z + w.w*p2.w;
      a3 += w.x*p3.x + w.y*p3.y + w.z*p3.z + w.w*p3.w;
    }
    g_qkv[(t0+0)*768 + j] = a0; g_qkv[(t0+1)*768 + j] = a1;
    g_qkv[(t0+2)*768 + j] = a2; g_qkv[(t0+3)*768 + j] = a3;
  }
}

// tiled transpose of K and V: kmat/vmat[c][u], coalesced both sides
__global__ __launch_bounds__(256) void ktrans_kernel(){
  __shared__ float tK[32][33];
  __shared__ float tV[32][33];
  const int bu = blockIdx.x, bc = blockIdx.y;
  const int tx = threadIdx.x & 31, ty = threadIdx.x >> 5;
  #pragma unroll
  for (int r=0; r<32; r+=8){
    int uu = bu*32 + ty + r;
    tK[ty+r][tx] = g_qkv[uu*768 + 256 + bc*32 + tx];
    tV[ty+r][tx] = g_qkv[uu*768 + 512 + bc*32 + tx];
  }
  __syncthreads();
  #pragma unroll
  for (int r=0; r<32; r+=8){
    int cc = bc*32 + ty + r;
    g_kmat[cc*512 + bu*32 + tx] = tK[tx][ty+r];
    g_vmat[cc*512 + bu*32 + tx] = tV[tx][ty+r];
  }
}

__global__ __launch_bounds__(512) void attn_kernel(float* __restrict__ out){
  const int t = blockIdx.x, u = threadIdx.x;
  const int lane = u & 63, wid = u >> 6;
  __shared__ float qsh[64];
  __shared__ float redm[8], reds[8];
  float accm = 0.f;
  for (int h=0; h<4; ++h){
    __syncthreads();
    if (u < 64) qsh[u] = g_qkv[t*3*E + h*64 + u];
    __syncthreads();
    const float* km = g_kmat + h*64*L + u;
    float s = 0.f;
    #pragma unroll 8
    for (int d=0; d<64; ++d) s += qsh[d]*km[d*L];
    s *= 0.125f;
    float m = s;
    for (int o=32;o;o>>=1) m = fmaxf(m, __shfl_xor(m, o, 64));
    if (lane == 0) redm[wid] = m;
    __syncthreads();
    m = redm[0];
    #pragma unroll
    for (int w2=1;w2<8;++w2) m = fmaxf(m, redm[w2]);
    float e = __expf(s - m);
    float sum = e;
    for (int o=32;o;o>>=1) sum += __shfl_xor(sum, o, 64);
    if (lane == 0) reds[wid] = sum;
    __syncthreads();
    sum = reds[0];
    #pragma unroll
    for (int w2=1;w2<8;++w2) sum += reds[w2];
    float a = e / sum;
    accm += 0.25f * a;
    if (t == L-1) g_a511[h*L + u] = a;
  }
  out[1 + t*L + u] = accm;
}

// PV row 511 via vmat rows (sequential float4 per thread) + out projection
__global__ __launch_bounds__(256) void head_kernel(const float* __restrict__ ow, const float* __restrict__ ob){
  __shared__ __align__(16) float ash[4*L];
  __shared__ float osh[E];
  const int tid = threadIdx.x;
  for (int i=tid; i<4*L; i+=256) ash[i] = g_a511[i];
  __syncthreads();
  const int h = tid >> 6, d = tid & 63;
  float o = 0.f;
  const float4* v4 = (const float4*)(g_vmat + (h*64+d)*L);
  const float4* a4 = (const float4*)(ash + h*L);
  #pragma unroll 4
  for (int uu=0; uu<128; ++uu){
    float4 v = v4[uu], a = a4[uu];
    o += a.x*v.x + a.y*v.y + a.z*v.z + a.w*v.w;
  }
  osh[tid] = o;
  __syncthreads();
  float m = ob[tid];
  const float* w = ow + tid*E;
  #pragma unroll 8
  for (int c2=0;c2<E;++c2) m += osh[c2]*w[c2];
  g_molemb[tid] = m;
}

// ---------------- final MLP (monolithic, round-7 passing version) ----------------
__global__ __launch_bounds__(640) void mlp_kernel(const float* __restrict__ smiles,
    const float* __restrict__ w1, const float* __restrict__ b1,
    const float* __restrict__ w2, const float* __restrict__ b2,
    const float* __restrict__ w3, const float* __restrict__ b3,
    const float* __restrict__ w4, const float* __restrict__ b4,
    float* __restrict__ out){
  __shared__ float f_sh[1152];
  __shared__ float a1[576];
  __shared__ float a2[256];
  __shared__ float a3[64];
  const int tid = threadIdx.x;
  if (tid < 256) f_sh[tid] = g_hg[tid];
  else if (tid < 512) f_sh[tid] = g_molemb[tid-256];
  if (tid < 638) f_sh[512 + tid] = smiles[tid];
  __syncthreads();
  if (tid < 575){
    float acc = b1[tid];
    const float2* w = (const float2*)(w1 + tid*1150);
    #pragma unroll 5
    for (int k=0;k<575;++k){ float2 wv = w[k]; acc += f_sh[2*k]*wv.x + f_sh[2*k+1]*wv.y; }
    a1[tid] = fmaxf(acc, 0.f);
  }
  __syncthreads();
  if (tid < 256){
    float acc = b2[tid];
    const float* w = w2 + tid*575;
    #pragma unroll 5
    for (int k=0;k<575;++k) acc += a1[k]*w[k];
    a2[tid] = fmaxf(acc, 0.f);
  }
  __syncthreads();
  if (tid < 64){
    float acc = b3[tid];
    const float* w = w3 + tid*256;
    #pragma unroll 8
    for (int k=0;k<256;++k) acc += a2[k]*w[k];
    a3[tid] = fmaxf(acc, 0.f);
  }
  __syncthreads();
  if (tid == 0){
    float acc = b4[0];
    #pragma unroll
    for (int k=0;k<64;++k) acc += a3[k]*w4[k];
    out[0] = acc;
  }
}

// ---------------- launch ----------------
extern "C" void kernel_launch(void* const* d_in, const int* in_sizes, int n_in,
                              void* d_out, int out_size, void* d_ws, size_t ws_size,
                              hipStream_t stream){
  (void)in_sizes; (void)n_in; (void)out_size; (void)d_ws; (void)ws_size;
  const float* g_mol   = (const float*)d_in[0];
  const float* feat    = (const float*)d_in[1];
  const float* smiles  = (const float*)d_in[2];
  const float* l0fWih  = (const float*)d_in[3];
  const float* l0fWhh  = (const float*)d_in[4];
  const float* l0fbih  = (const float*)d_in[5];
  const float* l0fbhh  = (const float*)d_in[6];
  const float* l0bWih  = (const float*)d_in[7];
  const float* l0bWhh  = (const float*)d_in[8];
  const float* l0bbih  = (const float*)d_in[9];
  const float* l0bbhh  = (const float*)d_in[10];
  const float* l1fWih  = (const float*)d_in[11];
  const float* l1fWhh  = (const float*)d_in[12];
  const float* l1fbih  = (const float*)d_in[13];
  const float* l1fbhh  = (const float*)d_in[14];
  const float* l1bWih  = (const float*)d_in[15];
  const float* l1bWhh  = (const float*)d_in[16];
  const float* l1bbih  = (const float*)d_in[17];
  const float* l1bbhh  = (const float*)d_in[18];
  const float* fcw     = (const float*)d_in[19];
  const float* fcb     = (const float*)d_in[20];
  const float* inw     = (const float*)d_in[21];
  const float* inb     = (const float*)d_in[22];
  const float* ow      = (const float*)d_in[23];
  const float* ob      = (const float*)d_in[24];
  const float* gc1w    = (const float*)d_in[25];
  const float* gc1b    = (const float*)d_in[26];
  const float* gc2w    = (const float*)d_in[27];
  const float* gc2b    = (const float*)d_in[28];
  const float* w1      = (const float*)d_in[29];
  const float* b1      = (const float*)d_in[30];
  const float* w2      = (const float*)d_in[31];
  const float* b2      = (const float*)d_in[32];
  const float* w3      = (const float*)d_in[33];
  const float* b3      = (const float*)d_in[34];
  const float* w4      = (const float*)d_in[35];
  const float* b4      = (const float*)d_in[36];
  const int*   src     = (const int*)d_in[37];
  const int*   dst     = (const int*)d_in[38];
  float* out = (float*)d_out;

  // GCN branch
  zero_kernel<<<196, 256, 0, stream>>>();
  hist_kernel<<<(NE+255)/256, 256, 0, stream>>>(src, dst);
  scan_kernel<<<1, 1024, 0, stream>>>();
  fill_kernel<<<(NE+255)/256, 256, 0, stream>>>(src, dst);
  agg_kernel<<<NN, 64, 0, stream>>>(feat);
  gemm1_kernel<<<NN/8, 256, 0, stream>>>(gc1w, gc1b);
  wsum_kernel<<<512, 128, 0, stream>>>();
  hg_kernel<<<1, 256, 0, stream>>>(gc2w, gc2b);

  // BiLSTM chain
  xg0_kernel<<<dim3(L,2), 512, 0, stream>>>(g_mol, l0fWih, l0fbih, l0fbhh, l0bWih, l0bbih, l0bbhh);
  lstm_kernel<<<2, 512, 0, stream>>>(l0fWhh, l0bWhh, 0);
  xg1_kernel<<<dim3(128,2), 512, 0, stream>>>(l1fWih, l1fbih, l1fbhh, l1bWih, l1bbih, l1bbhh);
  lstm_kernel<<<2, 512, 0, stream>>>(l1fWhh, l1bWhh, 1);

  // attention path
  proj_kernel<<<128, 256, 0, stream>>>(fcw, fcb);
  qkv_kernel<<<128, 256, 0, stream>>>(inw, inb);
  ktrans_kernel<<<dim3(16,8), 256, 0, stream>>>();
  attn_kernel<<<L, 512, 0, stream>>>(out);
  head_kernel<<<1, 256, 0, stream>>>(ow, ob);

  // final MLP
  mlp_kernel<<<1, 640, 0, stream>>>(smiles, w1, b1, w2, b2, w3, b3, w4, b4, out);
}